// Round 6
// baseline (392.912 us; speedup 1.0000x reference)
//
#include <hip/hip_runtime.h>
#include <math.h>

// Qnet: per-row tiny MLP + gumbel-sigmoid straight-through gates + 5 tiny experts.
//
// Round-5 post-mortem: split-kernel got VGPR 244->72 but left scalar stride-20B
// u-loads / soft-hard-stores (each wave instr touches ~20 cache lines) ->
// 2 TB/s, VALUBusy 44%, 165us. This round recombines the round-4 float4
// layout (4 rows/thread: u1/u2 = 5 exact float4 loads each, soft/hard = 5
// float4 stores each, out = 2 float4) with the lean fast-math path. The rare
// CR-f32 numpy simulation stays in a separate patch kernel (the correctness
// authority for |z| < 1e-4; fast-path z error ~1e-6, 100x margin).
// Floors: VALU ~50us (156 fma + ~38 quarter-rate trans per row), mem ~53us
// (333 MB at 6.3 TB/s).

constexpr float EPSF = 1e-8f;

__device__ __forceinline__ float fast_tanh(float a) {
    const float ea = __expf(-2.0f * fabsf(a));
    const float r = (1.0f - ea) * __builtin_amdgcn_rcpf(1.0f + ea);
    return copysignf(r, a);
}

__global__ __launch_bounds__(256) void qnet_main(
    const float* __restrict__ x,
    const float* __restrict__ u1,
    const float* __restrict__ u2,
    const float* __restrict__ fc1_w,    // [4][4]
    const float* __restrict__ fc1_b,    // [4]
    const float* __restrict__ picker_w, // [5][4]
    const float* __restrict__ picker_b, // [5]
    const float* __restrict__ ew1,      // [5][4][4]
    const float* __restrict__ eb1,      // [5][4]
    const float* __restrict__ ew2,      // [5][2][4]
    const float* __restrict__ eb2,      // [5][2]
    float* __restrict__ out_o,          // [B][2]
    float* __restrict__ hard_o,         // [B][5]
    float* __restrict__ soft_o,         // [B][5]
    unsigned* __restrict__ flag_cnt,    // d_ws[0]
    unsigned* __restrict__ flag_list,   // d_ws[1..]
    unsigned flag_cap)
{
    __shared__ float s_fc1w[16];
    __shared__ float s_fc1b[4];
    __shared__ float s_pw[20];
    __shared__ float s_pb[5];
    __shared__ float s_ew1[80];
    __shared__ float s_eb1[20];
    __shared__ float s_ew2[40];
    __shared__ float s_eb2[10];
    {
        const int tid = threadIdx.x;
        if (tid < 16) s_fc1w[tid] = fc1_w[tid];
        if (tid < 4)  s_fc1b[tid] = fc1_b[tid];
        if (tid < 20) s_pw[tid]   = picker_w[tid];
        if (tid < 5)  s_pb[tid]   = picker_b[tid];
        if (tid < 80) s_ew1[tid]  = ew1[tid];
        if (tid < 20) s_eb1[tid]  = eb1[tid];
        if (tid < 40) s_ew2[tid]  = ew2[tid];
        if (tid < 10) s_eb2[tid]  = eb2[tid];
    }
    __syncthreads();

    const unsigned t = blockIdx.x * blockDim.x + threadIdx.x;  // rows 4t..4t+3

    const float4* x4  = reinterpret_cast<const float4*>(x);
    const float4* u14 = reinterpret_cast<const float4*>(u1);
    const float4* u24 = reinterpret_cast<const float4*>(u2);

    float xr[4][4];
#pragma unroll
    for (int r = 0; r < 4; ++r) {
        float4 v = x4[4u * t + r];
        xr[r][0] = v.x; xr[r][1] = v.y; xr[r][2] = v.z; xr[r][3] = v.w;
    }
    float u1f[20], u2f[20];
#pragma unroll
    for (int k = 0; k < 5; ++k) {
        float4 a = u14[5u * t + k];
        u1f[4 * k + 0] = a.x; u1f[4 * k + 1] = a.y; u1f[4 * k + 2] = a.z; u1f[4 * k + 3] = a.w;
        float4 b = u24[5u * t + k];
        u2f[4 * k + 0] = b.x; u2f[4 * k + 1] = b.y; u2f[4 * k + 2] = b.z; u2f[4 * k + 3] = b.w;
    }

    float softf[20], hardf[20], outf[8];

#pragma unroll
    for (int r = 0; r < 4; ++r) {
        float h[4];
#pragma unroll
        for (int j = 0; j < 4; ++j) {
            float a = s_fc1b[j];
#pragma unroll
            for (int i = 0; i < 4; ++i) a += xr[r][i] * s_fc1w[4 * j + i];
            h[j] = fast_tanh(a);
        }

        float o0 = 0.0f, o1 = 0.0f;
#pragma unroll
        for (int c = 0; c < 5; ++c) {
            float lg = s_pb[c];
#pragma unroll
            for (int j = 0; j < 4; ++j) lg += h[j] * s_pw[4 * c + j];

            const float uu1 = u1f[5 * r + c];
            const float uu2 = u2f[5 * r + c];
            const float t1 = -__logf(uu1 + EPSF);   // > 0 (u < 1)
            const float t2 = -__logf(uu2 + EPSF);
            const float g1 = -__logf(t1 + EPSF);
            const float g2 = -__logf(t2 + EPSF);
            const float z = lg + (g1 - g2);

            const float sft = __builtin_amdgcn_rcpf(1.0f + __expf(-z));
            const float hrd = (z >= 0.0f) ? 1.0f : 0.0f;

            if (__builtin_expect(fabsf(z) < 1e-4f, 0)) {
                const unsigned slot = atomicAdd(flag_cnt, 1u);
                if (slot < flag_cap)
                    flag_list[slot] = (((4u * t + r) * 5u + c) << 1) | (z >= 0.0f ? 1u : 0u);
            }

            softf[5 * r + c] = sft;
            hardf[5 * r + c] = hrd;

            float eh[4];
#pragma unroll
            for (int k = 0; k < 4; ++k) {
                float a = s_eb1[4 * c + k];
#pragma unroll
                for (int j = 0; j < 4; ++j) a += h[j] * s_ew1[16 * c + 4 * k + j];
                eh[k] = fmaxf(a, 0.0f);
            }
            float e0 = s_eb2[2 * c + 0];
            float e1 = s_eb2[2 * c + 1];
#pragma unroll
            for (int k = 0; k < 4; ++k) {
                e0 += eh[k] * s_ew2[8 * c + 0 + k];
                e1 += eh[k] * s_ew2[8 * c + 4 + k];
            }
            o0 += hrd * e0;
            o1 += hrd * e1;
        }
        outf[2 * r + 0] = o0;
        outf[2 * r + 1] = o1;
    }

    float4* out4  = reinterpret_cast<float4*>(out_o);
    float4* hard4 = reinterpret_cast<float4*>(hard_o);
    float4* soft4 = reinterpret_cast<float4*>(soft_o);
    out4[2u * t + 0] = make_float4(outf[0], outf[1], outf[2], outf[3]);
    out4[2u * t + 1] = make_float4(outf[4], outf[5], outf[6], outf[7]);
#pragma unroll
    for (int k = 0; k < 5; ++k) {
        hard4[5u * t + k] = make_float4(hardf[4 * k + 0], hardf[4 * k + 1], hardf[4 * k + 2], hardf[4 * k + 3]);
        soft4[5u * t + k] = make_float4(softf[4 * k + 0], softf[4 * k + 1], softf[4 * k + 2], softf[4 * k + 3]);
    }
}

// ---- rare patch kernel: bit-exact CR-f32 numpy simulation (authority) ----
__global__ __launch_bounds__(256) void qnet_patch(
    const float* __restrict__ x,
    const float* __restrict__ u1,
    const float* __restrict__ u2,
    const float* __restrict__ fc1_w,
    const float* __restrict__ fc1_b,
    const float* __restrict__ picker_w,
    const float* __restrict__ picker_b,
    const float* __restrict__ ew1,
    const float* __restrict__ eb1,
    const float* __restrict__ ew2,
    const float* __restrict__ eb2,
    float* __restrict__ out_o,
    float* __restrict__ hard_o,
    float* __restrict__ soft_o,
    const unsigned* __restrict__ flag_cnt,
    const unsigned* __restrict__ flag_list,
    unsigned flag_cap)
{
    const unsigned n = min(flag_cnt[0], flag_cap);
    const unsigned stride = gridDim.x * blockDim.x;
    for (unsigned i = blockIdx.x * blockDim.x + threadIdx.x; i < n; i += stride) {
        const unsigned e = flag_list[i];
        const float fasthard = (e & 1u) ? 1.0f : 0.0f;
        const unsigned idx5 = e >> 1;
        const unsigned row = idx5 / 5u;
        const unsigned c = idx5 % 5u;

        const float4 xv = reinterpret_cast<const float4*>(x)[row];
        const float xr[4] = {xv.x, xv.y, xv.z, xv.w};
        const float uu1 = u1[idx5];
        const float uu2 = u2[idx5];

        float h32[4];
#pragma unroll
        for (int j = 0; j < 4; ++j) {
            float acc = 0.0f;
#pragma unroll
            for (int i2 = 0; i2 < 4; ++i2)
                acc = fmaf(xr[i2], fc1_w[4 * j + i2], acc);
            const float hpre = acc + fc1_b[j];
            h32[j] = (float)tanh((double)hpre);
        }
        float lacc = 0.0f;
#pragma unroll
        for (int j = 0; j < 4; ++j)
            lacc = fmaf(h32[j], picker_w[4 * c + j], lacc);
        const float lg32 = lacc + picker_b[c];
        const float a1 = uu1 + EPSF;
        const float l1 = (float)log((double)a1);
        const float b1 = (-l1) + EPSF;
        const float g1s = -((float)log((double)b1));
        const float a2 = uu2 + EPSF;
        const float l2 = (float)log((double)a2);
        const float b2 = (-l2) + EPSF;
        const float g2s = -((float)log((double)b2));
        const float dd = g1s - g2s;
        const float z32 = lg32 + dd;
        const float e32 = (float)exp((double)(-z32));
        const float den = 1.0f + e32;
        const float s32 = 1.0f / den;
        const float crhard = (s32 >= 0.5f) ? 1.0f : 0.0f;

        soft_o[idx5] = s32;
        hard_o[idx5] = crhard;

        if (crhard != fasthard) {
            float eh[4];
#pragma unroll
            for (int k = 0; k < 4; ++k) {
                float a = eb1[4 * c + k];
#pragma unroll
                for (int j = 0; j < 4; ++j) a += h32[j] * ew1[16 * c + 4 * k + j];
                eh[k] = fmaxf(a, 0.0f);
            }
            float e0 = eb2[2 * c + 0];
            float e1 = eb2[2 * c + 1];
#pragma unroll
            for (int k = 0; k < 4; ++k) {
                e0 += eh[k] * ew2[8 * c + 0 + k];
                e1 += eh[k] * ew2[8 * c + 4 + k];
            }
            const float d = crhard - fasthard;   // +1 or -1
            atomicAdd(&out_o[2u * row + 0], d * e0);
            atomicAdd(&out_o[2u * row + 1], d * e1);
        }
    }
}

extern "C" void kernel_launch(void* const* d_in, const int* in_sizes, int n_in,
                              void* d_out, int out_size, void* d_ws, size_t ws_size,
                              hipStream_t stream) {
    const float* x        = (const float*)d_in[0];
    const float* u1       = (const float*)d_in[1];
    const float* u2       = (const float*)d_in[2];
    const float* fc1_w    = (const float*)d_in[3];
    const float* fc1_b    = (const float*)d_in[4];
    const float* picker_w = (const float*)d_in[5];
    const float* picker_b = (const float*)d_in[6];
    const float* ew1      = (const float*)d_in[7];
    const float* eb1      = (const float*)d_in[8];
    const float* ew2      = (const float*)d_in[9];
    const float* eb2      = (const float*)d_in[10];

    const long long B = in_sizes[0] / 4;        // rows
    float* out  = (float*)d_out;                // [B][2]
    float* hard = out + (size_t)B * 2;          // [B][5]
    float* soft = hard + (size_t)B * 5;         // [B][5]

    unsigned* flag_cnt  = (unsigned*)d_ws;
    unsigned* flag_list = flag_cnt + 1;
    const unsigned flag_cap = (unsigned)(ws_size / 4 - 1);

    hipMemsetAsync(d_ws, 0, 4, stream);         // zero the counter (capturable)

    const int threads = 256;
    const long long nthreads = B / 4;           // 4 rows per thread
    const int blocks = (int)((nthreads + threads - 1) / threads);
    qnet_main<<<blocks, threads, 0, stream>>>(
        x, u1, u2, fc1_w, fc1_b, picker_w, picker_b,
        ew1, eb1, ew2, eb2, out, hard, soft,
        flag_cnt, flag_list, flag_cap);

    qnet_patch<<<128, 256, 0, stream>>>(
        x, u1, u2, fc1_w, fc1_b, picker_w, picker_b,
        ew1, eb1, ew2, eb2, out, hard, soft,
        flag_cnt, flag_list, flag_cap);
}

// Round 7
// 179.928 us; speedup vs baseline: 2.1837x; 2.1837x over previous
//
#include <hip/hip_runtime.h>
#include <math.h>

// Qnet: per-row tiny MLP + gumbel-sigmoid straight-through gates + 5 tiny experts.
//
// Round-6 post-mortem: 4-rows/thread + flag atomics spilled (VGPR=256,
// FETCH 114->352MB scratch traffic, 440us). Round-5 (1 row/thread, 72 VGPR)
// was 165us but paid stride-20B scalar u-loads and soft/hard stores.
// This round: 1 row/thread + LDS STAGING for the stride-20 streams.
//   - block = 256 threads = 256 rows
//   - u1/u2: cooperative 320x float4 loads -> LDS; per-thread reads at
//     tid*5+c (stride 5 is bijective mod 32 banks -> conflict-free;
//     wave-half 2-way aliasing is free per m136)
//   - soft/hard: per-thread LDS writes, then cooperative 320x float4 stores
//   - x load (float4/lane) and out store (float2/lane) stay direct
// Per-thread live state ~15 floats -> no spill. LDS 20.5KB/block.
// Rare |z|<1e-4 gates go to the flag list; patch kernel (bit-exact CR-f32
// numpy simulation) is the correctness authority near the boundary.

constexpr float EPSF = 1e-8f;

__device__ __forceinline__ float fast_tanh(float a) {
    const float ea = __expf(-2.0f * fabsf(a));
    const float r = (1.0f - ea) * __builtin_amdgcn_rcpf(1.0f + ea);
    return copysignf(r, a);
}

__global__ __launch_bounds__(256) void qnet_main(
    const float* __restrict__ x,
    const float* __restrict__ u1,
    const float* __restrict__ u2,
    const float* __restrict__ fc1_w,    // [4][4]
    const float* __restrict__ fc1_b,    // [4]
    const float* __restrict__ picker_w, // [5][4]
    const float* __restrict__ picker_b, // [5]
    const float* __restrict__ ew1,      // [5][4][4]
    const float* __restrict__ eb1,      // [5][4]
    const float* __restrict__ ew2,      // [5][2][4]
    const float* __restrict__ eb2,      // [5][2]
    float* __restrict__ out_o,          // [B][2]
    float* __restrict__ hard_o,         // [B][5]
    float* __restrict__ soft_o,         // [B][5]
    unsigned* __restrict__ flag_cnt,    // d_ws[0]
    unsigned* __restrict__ flag_list,   // d_ws[1..]
    unsigned flag_cap)
{
    __shared__ float s_fc1w[16];
    __shared__ float s_fc1b[4];
    __shared__ float s_pw[20];
    __shared__ float s_pb[5];
    __shared__ float s_ew1[80];
    __shared__ float s_eb1[20];
    __shared__ float s_ew2[40];
    __shared__ float s_eb2[10];
    __shared__ float s_u1[1280];   // 256 rows * 5
    __shared__ float s_u2[1280];
    __shared__ float s_soft[1280];
    __shared__ float s_hard[1280];

    const unsigned tid = threadIdx.x;
    {
        if (tid < 16) s_fc1w[tid] = fc1_w[tid];
        if (tid < 4)  s_fc1b[tid] = fc1_b[tid];
        if (tid < 20) s_pw[tid]   = picker_w[tid];
        if (tid < 5)  s_pb[tid]   = picker_b[tid];
        if (tid < 80) s_ew1[tid]  = ew1[tid];
        if (tid < 20) s_eb1[tid]  = eb1[tid];
        if (tid < 40) s_ew2[tid]  = ew2[tid];
        if (tid < 10) s_eb2[tid]  = eb2[tid];
    }

    const unsigned row0 = blockIdx.x * 256u;
    const unsigned row  = row0 + tid;

    // cooperative float4 staging of u1,u2 (320 float4 each per block)
    {
        const float4* u14 = reinterpret_cast<const float4*>(u1) + (size_t)row0 * 5u / 4u;
        const float4* u24 = reinterpret_cast<const float4*>(u2) + (size_t)row0 * 5u / 4u;
        float4* l1 = reinterpret_cast<float4*>(s_u1);
        float4* l2 = reinterpret_cast<float4*>(s_u2);
        l1[tid] = u14[tid];
        l2[tid] = u24[tid];
        if (tid < 64u) {
            l1[256u + tid] = u14[256u + tid];
            l2[256u + tid] = u24[256u + tid];
        }
    }
    __syncthreads();

    const float4 xv = reinterpret_cast<const float4*>(x)[row];
    const float xr[4] = {xv.x, xv.y, xv.z, xv.w};

    float h[4];
#pragma unroll
    for (int j = 0; j < 4; ++j) {
        float a = s_fc1b[j];
#pragma unroll
        for (int i = 0; i < 4; ++i) a += xr[i] * s_fc1w[4 * j + i];
        h[j] = fast_tanh(a);
    }

    float o0 = 0.0f, o1 = 0.0f;
#pragma unroll
    for (int c = 0; c < 5; ++c) {
        float lg = s_pb[c];
#pragma unroll
        for (int j = 0; j < 4; ++j) lg += h[j] * s_pw[4 * c + j];

        const float uu1 = s_u1[5u * tid + c];
        const float uu2 = s_u2[5u * tid + c];
        const float t1 = -__logf(uu1 + EPSF);   // > 0 (u < 1)
        const float t2 = -__logf(uu2 + EPSF);
        const float g1 = -__logf(t1 + EPSF);
        const float g2 = -__logf(t2 + EPSF);
        const float z = lg + (g1 - g2);

        const float sft = __builtin_amdgcn_rcpf(1.0f + __expf(-z));
        const float hrd = (z >= 0.0f) ? 1.0f : 0.0f;

        if (__builtin_expect(fabsf(z) < 1e-4f, 0)) {
            const unsigned slot = atomicAdd(flag_cnt, 1u);
            if (slot < flag_cap)
                flag_list[slot] = ((5u * row + c) << 1) | (z >= 0.0f ? 1u : 0u);
        }

        s_soft[5u * tid + c] = sft;
        s_hard[5u * tid + c] = hrd;

        float eh[4];
#pragma unroll
        for (int k = 0; k < 4; ++k) {
            float a = s_eb1[4 * c + k];
#pragma unroll
            for (int j = 0; j < 4; ++j) a += h[j] * s_ew1[16 * c + 4 * k + j];
            eh[k] = fmaxf(a, 0.0f);
        }
        float e0 = s_eb2[2 * c + 0];
        float e1 = s_eb2[2 * c + 1];
#pragma unroll
        for (int k = 0; k < 4; ++k) {
            e0 += eh[k] * s_ew2[8 * c + 0 + k];
            e1 += eh[k] * s_ew2[8 * c + 4 + k];
        }
        o0 += hrd * e0;
        o1 += hrd * e1;
    }

    reinterpret_cast<float2*>(out_o)[row] = make_float2(o0, o1);

    __syncthreads();

    // cooperative float4 stores of soft,hard
    {
        float4* g_s = reinterpret_cast<float4*>(soft_o) + (size_t)row0 * 5u / 4u;
        float4* g_h = reinterpret_cast<float4*>(hard_o) + (size_t)row0 * 5u / 4u;
        const float4* l_s = reinterpret_cast<const float4*>(s_soft);
        const float4* l_h = reinterpret_cast<const float4*>(s_hard);
        g_s[tid] = l_s[tid];
        g_h[tid] = l_h[tid];
        if (tid < 64u) {
            g_s[256u + tid] = l_s[256u + tid];
            g_h[256u + tid] = l_h[256u + tid];
        }
    }
}

// ---- rare patch kernel: bit-exact CR-f32 numpy simulation (authority) ----
__global__ __launch_bounds__(256) void qnet_patch(
    const float* __restrict__ x,
    const float* __restrict__ u1,
    const float* __restrict__ u2,
    const float* __restrict__ fc1_w,
    const float* __restrict__ fc1_b,
    const float* __restrict__ picker_w,
    const float* __restrict__ picker_b,
    const float* __restrict__ ew1,
    const float* __restrict__ eb1,
    const float* __restrict__ ew2,
    const float* __restrict__ eb2,
    float* __restrict__ out_o,
    float* __restrict__ hard_o,
    float* __restrict__ soft_o,
    const unsigned* __restrict__ flag_cnt,
    const unsigned* __restrict__ flag_list,
    unsigned flag_cap)
{
    const unsigned n = min(flag_cnt[0], flag_cap);
    const unsigned stride = gridDim.x * blockDim.x;
    for (unsigned i = blockIdx.x * blockDim.x + threadIdx.x; i < n; i += stride) {
        const unsigned e = flag_list[i];
        const float fasthard = (e & 1u) ? 1.0f : 0.0f;
        const unsigned idx5 = e >> 1;
        const unsigned row = idx5 / 5u;
        const unsigned c = idx5 % 5u;

        const float4 xv = reinterpret_cast<const float4*>(x)[row];
        const float xr[4] = {xv.x, xv.y, xv.z, xv.w};
        const float uu1 = u1[idx5];
        const float uu2 = u2[idx5];

        float h32[4];
#pragma unroll
        for (int j = 0; j < 4; ++j) {
            float acc = 0.0f;
#pragma unroll
            for (int i2 = 0; i2 < 4; ++i2)
                acc = fmaf(xr[i2], fc1_w[4 * j + i2], acc);
            const float hpre = acc + fc1_b[j];
            h32[j] = (float)tanh((double)hpre);
        }
        float lacc = 0.0f;
#pragma unroll
        for (int j = 0; j < 4; ++j)
            lacc = fmaf(h32[j], picker_w[4 * c + j], lacc);
        const float lg32 = lacc + picker_b[c];
        const float a1 = uu1 + EPSF;
        const float l1 = (float)log((double)a1);
        const float b1 = (-l1) + EPSF;
        const float g1s = -((float)log((double)b1));
        const float a2 = uu2 + EPSF;
        const float l2 = (float)log((double)a2);
        const float b2 = (-l2) + EPSF;
        const float g2s = -((float)log((double)b2));
        const float dd = g1s - g2s;
        const float z32 = lg32 + dd;
        const float e32 = (float)exp((double)(-z32));
        const float den = 1.0f + e32;
        const float s32 = 1.0f / den;
        const float crhard = (s32 >= 0.5f) ? 1.0f : 0.0f;

        soft_o[idx5] = s32;
        hard_o[idx5] = crhard;

        if (crhard != fasthard) {
            float eh[4];
#pragma unroll
            for (int k = 0; k < 4; ++k) {
                float a = eb1[4 * c + k];
#pragma unroll
                for (int j = 0; j < 4; ++j) a += h32[j] * ew1[16 * c + 4 * k + j];
                eh[k] = fmaxf(a, 0.0f);
            }
            float e0 = eb2[2 * c + 0];
            float e1 = eb2[2 * c + 1];
#pragma unroll
            for (int k = 0; k < 4; ++k) {
                e0 += eh[k] * ew2[8 * c + 0 + k];
                e1 += eh[k] * ew2[8 * c + 4 + k];
            }
            const float d = crhard - fasthard;   // +1 or -1
            atomicAdd(&out_o[2u * row + 0], d * e0);
            atomicAdd(&out_o[2u * row + 1], d * e1);
        }
    }
}

extern "C" void kernel_launch(void* const* d_in, const int* in_sizes, int n_in,
                              void* d_out, int out_size, void* d_ws, size_t ws_size,
                              hipStream_t stream) {
    const float* x        = (const float*)d_in[0];
    const float* u1       = (const float*)d_in[1];
    const float* u2       = (const float*)d_in[2];
    const float* fc1_w    = (const float*)d_in[3];
    const float* fc1_b    = (const float*)d_in[4];
    const float* picker_w = (const float*)d_in[5];
    const float* picker_b = (const float*)d_in[6];
    const float* ew1      = (const float*)d_in[7];
    const float* eb1      = (const float*)d_in[8];
    const float* ew2      = (const float*)d_in[9];
    const float* eb2      = (const float*)d_in[10];

    const long long B = in_sizes[0] / 4;        // rows
    float* out  = (float*)d_out;                // [B][2]
    float* hard = out + (size_t)B * 2;          // [B][5]
    float* soft = hard + (size_t)B * 5;         // [B][5]

    unsigned* flag_cnt  = (unsigned*)d_ws;
    unsigned* flag_list = flag_cnt + 1;
    const unsigned flag_cap = (unsigned)(ws_size / 4 - 1);

    hipMemsetAsync(d_ws, 0, 4, stream);         // zero the counter (capturable)

    const int threads = 256;
    const int blocks = (int)((B + threads - 1) / threads);
    qnet_main<<<blocks, threads, 0, stream>>>(
        x, u1, u2, fc1_w, fc1_b, picker_w, picker_b,
        ew1, eb1, ew2, eb2, out, hard, soft,
        flag_cnt, flag_list, flag_cap);

    qnet_patch<<<128, 256, 0, stream>>>(
        x, u1, u2, fc1_w, fc1_b, picker_w, picker_b,
        ew1, eb1, ew2, eb2, out, hard, soft,
        flag_cnt, flag_list, flag_cap);
}

// Round 8
// 123.367 us; speedup vs baseline: 3.1849x; 1.4585x over previous
//
#include <hip/hip_runtime.h>
#include <math.h>

// Qnet: per-row tiny MLP + gumbel-sigmoid straight-through gates + 5 tiny experts.
//
// Round-7 post-mortem: LDS weight staging was the hidden tax — ~195
// ds_read_b32 per wave (~1100 cyc) re-loading FMA operands. FETCH stayed
// ~114MB with or without coalescing games (L2/L3 absorb the stride-20B
// streams), so the fix is issue-cost, not bytes:
//   1. NO LDS. Weights read directly at uniform indices -> compiler emits
//      s_load into SGPRs (scalar pipe + scalar cache; VALU reads SGPR
//      operands for free).
//   2. e-domain gumbel: exp(-z) = exp(-lg)*(t1+eps)/(t2+eps)  [exact
//      identity] -> 3 trans/gate instead of 5; 19 trans/row total (was 29).
//      hard = (e <= 1), soft = rcp(1+e), flag window |e-1| < 1.05e-4
//      (fast-path rel err ~1e-6, 100x margin; np dead band ~2e-7).
//   3. 2 rows/thread: float4 x/out, float2 u/soft/hard (all aligned),
//      ~75 live floats -> no spill (round-6 lesson: 4 rows spills).
// Rare flagged gates -> patch kernel = bit-exact CR-f32 numpy simulation
// (the correctness authority near the boundary).

constexpr float EPSF = 1e-8f;

__device__ __forceinline__ float fast_tanh(float a) {
    const float ea = __expf(-2.0f * fabsf(a));
    const float r = (1.0f - ea) * __builtin_amdgcn_rcpf(1.0f + ea);
    return copysignf(r, a);
}

__global__ __launch_bounds__(256) void qnet_main(
    const float* __restrict__ x,
    const float* __restrict__ u1,
    const float* __restrict__ u2,
    const float* __restrict__ fc1_w,    // [4][4]
    const float* __restrict__ fc1_b,    // [4]
    const float* __restrict__ picker_w, // [5][4]
    const float* __restrict__ picker_b, // [5]
    const float* __restrict__ ew1,      // [5][4][4]
    const float* __restrict__ eb1,      // [5][4]
    const float* __restrict__ ew2,      // [5][2][4]
    const float* __restrict__ eb2,      // [5][2]
    float* __restrict__ out_o,          // [B][2]
    float* __restrict__ hard_o,         // [B][5]
    float* __restrict__ soft_o,         // [B][5]
    unsigned* __restrict__ flag_cnt,    // d_ws[0]
    unsigned* __restrict__ flag_list,   // d_ws[1..]
    unsigned flag_cap)
{
    const unsigned t = blockIdx.x * blockDim.x + threadIdx.x;  // rows 2t, 2t+1

    // ---- loads: float4 x, float2 u (all naturally aligned) ----
    const float4* x4 = reinterpret_cast<const float4*>(x);
    const float2* u12 = reinterpret_cast<const float2*>(u1);
    const float2* u22 = reinterpret_cast<const float2*>(u2);

    float xr[2][4];
#pragma unroll
    for (int r = 0; r < 2; ++r) {
        float4 v = x4[2u * t + r];
        xr[r][0] = v.x; xr[r][1] = v.y; xr[r][2] = v.z; xr[r][3] = v.w;
    }
    float u1f[10], u2f[10];
#pragma unroll
    for (int k = 0; k < 5; ++k) {
        float2 a = u12[5u * t + k];
        u1f[2 * k + 0] = a.x; u1f[2 * k + 1] = a.y;
        float2 b = u22[5u * t + k];
        u2f[2 * k + 0] = b.x; u2f[2 * k + 1] = b.y;
    }

    float softf[10], hardf[10], outf[4];

#pragma unroll
    for (int r = 0; r < 2; ++r) {
        // h = tanh(fc1(x)) — weights read at uniform indices (s_load/SGPR)
        float h[4];
#pragma unroll
        for (int j = 0; j < 4; ++j) {
            float a = fc1_b[j];
#pragma unroll
            for (int i = 0; i < 4; ++i) a += xr[r][i] * fc1_w[4 * j + i];
            h[j] = fast_tanh(a);
        }

        float o0 = 0.0f, o1 = 0.0f;
#pragma unroll
        for (int c = 0; c < 5; ++c) {
            float lg = picker_b[c];
#pragma unroll
            for (int j = 0; j < 4; ++j) lg += h[j] * picker_w[4 * c + j];

            const float uu1 = u1f[5 * r + c];
            const float uu2 = u2f[5 * r + c];
            const float t1 = -__logf(uu1 + EPSF);   // > 0 (u < 1)
            const float t2 = -__logf(uu2 + EPSF);
            // exp(-z) = exp(-lg) * (t1+eps) / (t2+eps)   [exact identity]
            const float e = __expf(-lg) * (t1 + EPSF) *
                            __builtin_amdgcn_rcpf(t2 + EPSF);
            const float sft = __builtin_amdgcn_rcpf(1.0f + e);
            const float hrd = (e <= 1.0f) ? 1.0f : 0.0f;

            if (__builtin_expect(fabsf(e - 1.0f) < 1.05e-4f, 0)) {
                const unsigned slot = atomicAdd(flag_cnt, 1u);
                if (slot < flag_cap)
                    flag_list[slot] = (((2u * t + r) * 5u + c) << 1) |
                                      (e <= 1.0f ? 1u : 0u);
            }

            softf[5 * r + c] = sft;
            hardf[5 * r + c] = hrd;

            // expert c: Linear(4,4)->ReLU->Linear(4,2)
            float eh[4];
#pragma unroll
            for (int k = 0; k < 4; ++k) {
                float a = eb1[4 * c + k];
#pragma unroll
                for (int j = 0; j < 4; ++j) a += h[j] * ew1[16 * c + 4 * k + j];
                eh[k] = fmaxf(a, 0.0f);
            }
            float e0 = eb2[2 * c + 0];
            float e1 = eb2[2 * c + 1];
#pragma unroll
            for (int k = 0; k < 4; ++k) {
                e0 += eh[k] * ew2[8 * c + 0 + k];
                e1 += eh[k] * ew2[8 * c + 4 + k];
            }
            o0 += hrd * e0;
            o1 += hrd * e1;
        }
        outf[2 * r + 0] = o0;
        outf[2 * r + 1] = o1;
    }

    // ---- stores: float4 out, float2 soft/hard ----
    reinterpret_cast<float4*>(out_o)[t] = make_float4(outf[0], outf[1], outf[2], outf[3]);
    float2* s2 = reinterpret_cast<float2*>(soft_o);
    float2* h2 = reinterpret_cast<float2*>(hard_o);
#pragma unroll
    for (int k = 0; k < 5; ++k) {
        s2[5u * t + k] = make_float2(softf[2 * k + 0], softf[2 * k + 1]);
        h2[5u * t + k] = make_float2(hardf[2 * k + 0], hardf[2 * k + 1]);
    }
}

// ---- rare patch kernel: bit-exact CR-f32 numpy simulation (authority) ----
__global__ __launch_bounds__(256) void qnet_patch(
    const float* __restrict__ x,
    const float* __restrict__ u1,
    const float* __restrict__ u2,
    const float* __restrict__ fc1_w,
    const float* __restrict__ fc1_b,
    const float* __restrict__ picker_w,
    const float* __restrict__ picker_b,
    const float* __restrict__ ew1,
    const float* __restrict__ eb1,
    const float* __restrict__ ew2,
    const float* __restrict__ eb2,
    float* __restrict__ out_o,
    float* __restrict__ hard_o,
    float* __restrict__ soft_o,
    const unsigned* __restrict__ flag_cnt,
    const unsigned* __restrict__ flag_list,
    unsigned flag_cap)
{
    const unsigned n = min(flag_cnt[0], flag_cap);
    const unsigned stride = gridDim.x * blockDim.x;
    for (unsigned i = blockIdx.x * blockDim.x + threadIdx.x; i < n; i += stride) {
        const unsigned e = flag_list[i];
        const float fasthard = (e & 1u) ? 1.0f : 0.0f;
        const unsigned idx5 = e >> 1;
        const unsigned row = idx5 / 5u;
        const unsigned c = idx5 % 5u;

        const float4 xv = reinterpret_cast<const float4*>(x)[row];
        const float xr[4] = {xv.x, xv.y, xv.z, xv.w};
        const float uu1 = u1[idx5];
        const float uu2 = u2[idx5];

        float h32[4];
#pragma unroll
        for (int j = 0; j < 4; ++j) {
            float acc = 0.0f;
#pragma unroll
            for (int i2 = 0; i2 < 4; ++i2)
                acc = fmaf(xr[i2], fc1_w[4 * j + i2], acc);
            const float hpre = acc + fc1_b[j];
            h32[j] = (float)tanh((double)hpre);
        }
        float lacc = 0.0f;
#pragma unroll
        for (int j = 0; j < 4; ++j)
            lacc = fmaf(h32[j], picker_w[4 * c + j], lacc);
        const float lg32 = lacc + picker_b[c];
        const float a1 = uu1 + EPSF;
        const float l1 = (float)log((double)a1);
        const float b1 = (-l1) + EPSF;
        const float g1s = -((float)log((double)b1));
        const float a2 = uu2 + EPSF;
        const float l2 = (float)log((double)a2);
        const float b2 = (-l2) + EPSF;
        const float g2s = -((float)log((double)b2));
        const float dd = g1s - g2s;
        const float z32 = lg32 + dd;
        const float e32 = (float)exp((double)(-z32));
        const float den = 1.0f + e32;
        const float s32 = 1.0f / den;
        const float crhard = (s32 >= 0.5f) ? 1.0f : 0.0f;

        soft_o[idx5] = s32;
        hard_o[idx5] = crhard;

        if (crhard != fasthard) {
            float eh[4];
#pragma unroll
            for (int k = 0; k < 4; ++k) {
                float a = eb1[4 * c + k];
#pragma unroll
                for (int j = 0; j < 4; ++j) a += h32[j] * ew1[16 * c + 4 * k + j];
                eh[k] = fmaxf(a, 0.0f);
            }
            float e0 = eb2[2 * c + 0];
            float e1 = eb2[2 * c + 1];
#pragma unroll
            for (int k = 0; k < 4; ++k) {
                e0 += eh[k] * ew2[8 * c + 0 + k];
                e1 += eh[k] * ew2[8 * c + 4 + k];
            }
            const float d = crhard - fasthard;   // +1 or -1
            atomicAdd(&out_o[2u * row + 0], d * e0);
            atomicAdd(&out_o[2u * row + 1], d * e1);
        }
    }
}

extern "C" void kernel_launch(void* const* d_in, const int* in_sizes, int n_in,
                              void* d_out, int out_size, void* d_ws, size_t ws_size,
                              hipStream_t stream) {
    const float* x        = (const float*)d_in[0];
    const float* u1       = (const float*)d_in[1];
    const float* u2       = (const float*)d_in[2];
    const float* fc1_w    = (const float*)d_in[3];
    const float* fc1_b    = (const float*)d_in[4];
    const float* picker_w = (const float*)d_in[5];
    const float* picker_b = (const float*)d_in[6];
    const float* ew1      = (const float*)d_in[7];
    const float* eb1      = (const float*)d_in[8];
    const float* ew2      = (const float*)d_in[9];
    const float* eb2      = (const float*)d_in[10];

    const long long B = in_sizes[0] / 4;        // rows
    float* out  = (float*)d_out;                // [B][2]
    float* hard = out + (size_t)B * 2;          // [B][5]
    float* soft = hard + (size_t)B * 5;         // [B][5]

    unsigned* flag_cnt  = (unsigned*)d_ws;
    unsigned* flag_list = flag_cnt + 1;
    const unsigned flag_cap = (unsigned)(ws_size / 4 - 1);

    hipMemsetAsync(d_ws, 0, 4, stream);         // zero the counter (capturable)

    const int threads = 256;
    const long long nthreads = B / 2;           // 2 rows per thread
    const int blocks = (int)((nthreads + threads - 1) / threads);
    qnet_main<<<blocks, threads, 0, stream>>>(
        x, u1, u2, fc1_w, fc1_b, picker_w, picker_b,
        ew1, eb1, ew2, eb2, out, hard, soft,
        flag_cnt, flag_list, flag_cap);

    qnet_patch<<<128, 256, 0, stream>>>(
        x, u1, u2, fc1_w, fc1_b, picker_w, picker_b,
        ew1, eb1, ew2, eb2, out, hard, soft,
        flag_cnt, flag_list, flag_cap);
}